// Round 1
// baseline (189.720 us; speedup 1.0000x reference)
//
#include <hip/hip_runtime.h>

// PyramidToDepth: x (8,512,512,2) fp32 -> out (8,18,512,512,1) fp32
// levels lv=0..8, S=512>>lv; out[b, 2*lv+c, h, w] = bilinear_up(level_lv)[b,h,w,c]
//
// Pyramid levels 1..8 live in d_ws, channel-interleaved (B,S,S,2) like x.
// Float offsets of level lv in d_ws (2*sum of 8*S'^2 float2 for finer levels):
//   lv:     1        2        3        4        5        6        7        8
//   off:    0  1048576  1310720  1376256  1392640  1396736  1397760  1398016
// Total: 1398080 floats = 5.59 MB of workspace.

#define HWTOT (512 * 512)

template <int S>
__global__ __launch_bounds__(256) void pool2x2(const float* __restrict__ src,
                                               float* __restrict__ dst) {
  int idx = blockIdx.x * blockDim.x + threadIdx.x;
  if (idx >= 8 * S * S) return;
  int j = idx & (S - 1);
  int t = idx / S;
  int i = t & (S - 1);
  int b = t / S;
  const int Sin = 2 * S;
  size_t base0 = ((size_t)(b * Sin + 2 * i) * Sin + 2 * j) * 2;  // floats
  size_t base1 = base0 + (size_t)Sin * 2;
  float4 a = *(const float4*)(src + base0);  // row 2i, cols 2j..2j+1, both ch
  float4 c = *(const float4*)(src + base1);  // row 2i+1
  float2 o;
  o.x = (a.x + a.z + c.x + c.z) * 0.25f;
  o.y = (a.y + a.w + c.y + c.w) * 0.25f;
  *(float2*)(dst + (size_t)idx * 2) = o;
}

__global__ __launch_bounds__(256) void upsample_all(const float* __restrict__ x,
                                                    const float2* __restrict__ pyr,
                                                    float* __restrict__ out) {
  const int w = blockIdx.x * blockDim.x + threadIdx.x;  // 0..511
  const int h = blockIdx.y;                             // 0..511 (wave-uniform)
  const int b = blockIdx.z;                             // 0..7

  const size_t obase = (size_t)b * 18 * HWTOT + (size_t)h * 512 + w;

  // level 0: identity resize
  float2 v0 = ((const float2*)x)[((size_t)b * 512 + h) * 512 + w];
  out[obase] = v0.x;
  out[obase + HWTOT] = v0.y;

  // float2-unit offsets of levels 1..8 inside pyr
  const int off2[9] = {0, 0, 524288, 655360, 688128, 696320, 698368, 698880, 699008};

#pragma unroll
  for (int lv = 1; lv <= 8; ++lv) {
    const int S = 512 >> lv;
    const float scale = 1.0f / (float)(1 << lv);
    // jax.image.resize bilinear: half-pixel centers + edge clamp
    float sh = ((float)h + 0.5f) * scale - 0.5f;
    float sw = ((float)w + 0.5f) * scale - 0.5f;
    float fh0 = floorf(sh), fw0 = floorf(sw);
    float fh = sh - fh0, fw = sw - fw0;
    int h0 = (int)fh0, w0 = (int)fw0;
    int h0c = h0 < 0 ? 0 : h0;
    int h1c = (h0 + 1 > S - 1) ? (S - 1) : (h0 + 1);
    int w0c = w0 < 0 ? 0 : w0;
    int w1c = (w0 + 1 > S - 1) ? (S - 1) : (w0 + 1);

    const float2* L = pyr + off2[lv];
    size_t r0 = (size_t)(b * S + h0c) * S;
    size_t r1 = (size_t)(b * S + h1c) * S;
    float2 v00 = L[r0 + w0c];
    float2 v01 = L[r0 + w1c];
    float2 v10 = L[r1 + w0c];
    float2 v11 = L[r1 + w1c];

    float wx0 = 1.0f - fw, wy0 = 1.0f - fh;
    float tx = v00.x * wx0 + v01.x * fw;
    float ty = v00.y * wx0 + v01.y * fw;
    float bx = v10.x * wx0 + v11.x * fw;
    float by = v10.y * wx0 + v11.y * fw;
    float rx = tx * wy0 + bx * fh;
    float ry = ty * wy0 + by * fh;

    out[obase + (size_t)(2 * lv) * HWTOT] = rx;
    out[obase + (size_t)(2 * lv + 1) * HWTOT] = ry;
  }
}

extern "C" void kernel_launch(void* const* d_in, const int* in_sizes, int n_in,
                              void* d_out, int out_size, void* d_ws, size_t ws_size,
                              hipStream_t stream) {
  const float* x = (const float*)d_in[0];
  float* out = (float*)d_out;
  float* pyr = (float*)d_ws;

  // float offsets of levels 1..8 in workspace
  const int offf[9] = {0, 0, 1048576, 1310720, 1376256, 1392640, 1396736, 1397760, 1398016};

  // pyramid cascade
  pool2x2<256><<<dim3((8 * 256 * 256 + 255) / 256), 256, 0, stream>>>(x, pyr + offf[1]);
  pool2x2<128><<<dim3((8 * 128 * 128 + 255) / 256), 256, 0, stream>>>(pyr + offf[1], pyr + offf[2]);
  pool2x2<64><<<dim3((8 * 64 * 64 + 255) / 256), 256, 0, stream>>>(pyr + offf[2], pyr + offf[3]);
  pool2x2<32><<<dim3((8 * 32 * 32 + 255) / 256), 256, 0, stream>>>(pyr + offf[3], pyr + offf[4]);
  pool2x2<16><<<dim3((8 * 16 * 16 + 255) / 256), 256, 0, stream>>>(pyr + offf[4], pyr + offf[5]);
  pool2x2<8><<<dim3((8 * 8 * 8 + 255) / 256), 256, 0, stream>>>(pyr + offf[5], pyr + offf[6]);
  pool2x2<4><<<dim3((8 * 4 * 4 + 255) / 256), 256, 0, stream>>>(pyr + offf[6], pyr + offf[7]);
  pool2x2<2><<<dim3((8 * 2 * 2 + 255) / 256), 256, 0, stream>>>(pyr + offf[7], pyr + offf[8]);

  // fused upsample + stack + transpose
  upsample_all<<<dim3(512 / 256, 512, 8), 256, 0, stream>>>(x, (const float2*)pyr, out);
}

// Round 3
// 178.935 us; speedup vs baseline: 1.0603x; 1.0603x over previous
//
#include <hip/hip_runtime.h>

// PyramidToDepth: x (8,512,512,2) fp32 -> out (8,18,512,512,1) fp32
// levels lv=0..8, S=512>>lv; out[b, 2*lv+c, h, w] = bilinear_up(level_lv)[b,h,w,c]
//
// d_ws holds levels 1..8, channel-interleaved (B,S,S,2), float2-unit offsets:
//   lv:    1       2       3       4       5       6       7       8
//   off2:  0  524288  655360  688128  696320  698368  698880  699008
// (699072 float2 = 5.59 MB total)

#define HWTOT (512 * 512)

// clang-native float4 for __builtin_nontemporal_store (HIP float4 is a class)
typedef float vfloat4 __attribute__((ext_vector_type(4)));

// --- Kernel A: levels 1..6, one block per 64x64 input tile -------------------
__global__ __launch_bounds__(256) void build_levels_1_6(const float* __restrict__ x,
                                                        float2* __restrict__ pyr) {
  const int b = blockIdx.y;
  const int tx = blockIdx.x & 7, ty = blockIdx.x >> 3;  // 8x8 tiles of 64x64
  const int t = threadIdx.x;

  __shared__ float2 sh1[32 * 32];
  __shared__ float2 sh2[16 * 16];
  __shared__ float2 sh3[8 * 8];
  __shared__ float2 sh4[4 * 4];
  __shared__ float2 sh5[2 * 2];

  // level 1: 32x32 tile-local, 4 consecutive cols per thread
  {
    const int i = t >> 3;
    const int j0 = (t & 7) << 2;
    const float* r0 = x + (((size_t)(b * 512 + ty * 64 + 2 * i)) * 512 + (tx * 64 + 2 * j0)) * 2;
    const float* r1 = r0 + 1024;  // next row (512 px * 2 ch)
    float2 o[4];
#pragma unroll
    for (int k = 0; k < 4; ++k) {
      float4 a = *(const float4*)(r0 + 4 * k);
      float4 c = *(const float4*)(r1 + 4 * k);
      o[k].x = (a.x + a.z + c.x + c.z) * 0.25f;
      o[k].y = (a.y + a.w + c.y + c.w) * 0.25f;
      sh1[i * 32 + j0 + k] = o[k];
    }
    float2* g = pyr + ((size_t)(b * 256 + ty * 32 + i) * 256 + tx * 32 + j0);
    *(float4*)(g) = make_float4(o[0].x, o[0].y, o[1].x, o[1].y);
    *(float4*)(g + 2) = make_float4(o[2].x, o[2].y, o[3].x, o[3].y);
  }
  __syncthreads();
  // level 2: 16x16
  {
    const int i = t >> 4, j = t & 15;
    float2 a = sh1[(2 * i) * 32 + 2 * j], c = sh1[(2 * i) * 32 + 2 * j + 1];
    float2 d = sh1[(2 * i + 1) * 32 + 2 * j], e = sh1[(2 * i + 1) * 32 + 2 * j + 1];
    float2 o = {(a.x + c.x + d.x + e.x) * 0.25f, (a.y + c.y + d.y + e.y) * 0.25f};
    sh2[i * 16 + j] = o;
    pyr[524288 + (size_t)(b * 128 + ty * 16 + i) * 128 + tx * 16 + j] = o;
  }
  __syncthreads();
  // level 3: 8x8
  if (t < 64) {
    const int i = t >> 3, j = t & 7;
    float2 a = sh2[(2 * i) * 16 + 2 * j], c = sh2[(2 * i) * 16 + 2 * j + 1];
    float2 d = sh2[(2 * i + 1) * 16 + 2 * j], e = sh2[(2 * i + 1) * 16 + 2 * j + 1];
    float2 o = {(a.x + c.x + d.x + e.x) * 0.25f, (a.y + c.y + d.y + e.y) * 0.25f};
    sh3[i * 8 + j] = o;
    pyr[655360 + (size_t)(b * 64 + ty * 8 + i) * 64 + tx * 8 + j] = o;
  }
  __syncthreads();
  // level 4: 4x4
  if (t < 16) {
    const int i = t >> 2, j = t & 3;
    float2 a = sh3[(2 * i) * 8 + 2 * j], c = sh3[(2 * i) * 8 + 2 * j + 1];
    float2 d = sh3[(2 * i + 1) * 8 + 2 * j], e = sh3[(2 * i + 1) * 8 + 2 * j + 1];
    float2 o = {(a.x + c.x + d.x + e.x) * 0.25f, (a.y + c.y + d.y + e.y) * 0.25f};
    sh4[i * 4 + j] = o;
    pyr[688128 + (size_t)(b * 32 + ty * 4 + i) * 32 + tx * 4 + j] = o;
  }
  __syncthreads();
  // level 5: 2x2
  if (t < 4) {
    const int i = t >> 1, j = t & 1;
    float2 a = sh4[(2 * i) * 4 + 2 * j], c = sh4[(2 * i) * 4 + 2 * j + 1];
    float2 d = sh4[(2 * i + 1) * 4 + 2 * j], e = sh4[(2 * i + 1) * 4 + 2 * j + 1];
    float2 o = {(a.x + c.x + d.x + e.x) * 0.25f, (a.y + c.y + d.y + e.y) * 0.25f};
    sh5[i * 2 + j] = o;
    pyr[696320 + (size_t)(b * 16 + ty * 2 + i) * 16 + tx * 2 + j] = o;
  }
  __syncthreads();
  // level 6: 1x1
  if (t == 0) {
    float2 a = sh5[0], c = sh5[1], d = sh5[2], e = sh5[3];
    float2 o = {(a.x + c.x + d.x + e.x) * 0.25f, (a.y + c.y + d.y + e.y) * 0.25f};
    pyr[698368 + (size_t)(b * 8 + ty) * 8 + tx] = o;
  }
}

// --- Kernel B: levels 7..8 from level 6, one block per image -----------------
__global__ __launch_bounds__(64) void build_levels_7_8(float2* __restrict__ pyr) {
  const int b = blockIdx.x;
  const int t = threadIdx.x;
  __shared__ float2 s7[16];
  const float2* l6 = pyr + 698368 + (size_t)b * 64;
  if (t < 16) {
    const int i = t >> 2, j = t & 3;
    float2 a = l6[(2 * i) * 8 + 2 * j], c = l6[(2 * i) * 8 + 2 * j + 1];
    float2 d = l6[(2 * i + 1) * 8 + 2 * j], e = l6[(2 * i + 1) * 8 + 2 * j + 1];
    float2 o = {(a.x + c.x + d.x + e.x) * 0.25f, (a.y + c.y + d.y + e.y) * 0.25f};
    s7[t] = o;
    pyr[698880 + (size_t)b * 16 + t] = o;
  }
  __syncthreads();
  if (t < 4) {
    const int i = t >> 1, j = t & 1;
    float2 a = s7[(2 * i) * 4 + 2 * j], c = s7[(2 * i) * 4 + 2 * j + 1];
    float2 d = s7[(2 * i + 1) * 4 + 2 * j], e = s7[(2 * i + 1) * 4 + 2 * j + 1];
    float2 o = {(a.x + c.x + d.x + e.x) * 0.25f, (a.y + c.y + d.y + e.y) * 0.25f};
    pyr[699008 + (size_t)b * 4 + t] = o;
  }
}

// --- Kernel C: fused upsample + stack, 4 w-pixels per thread -----------------
__global__ __launch_bounds__(256) void upsample_all(const float* __restrict__ x,
                                                    const float2* __restrict__ pyr,
                                                    float* __restrict__ out) {
  const int t = threadIdx.x;
  const int w0pix = (t & 127) << 2;                 // base of 4 consecutive w
  const int h = (blockIdx.x << 1) + (t >> 7);       // wave-uniform
  const int b = blockIdx.y;
  const size_t obase = (size_t)b * 18 * HWTOT + (size_t)h * 512 + w0pix;

  // level 0: identity
  {
    const float* px = x + (((size_t)b * 512 + h) * 512 + w0pix) * 2;
    float4 a = *(const float4*)px;        // w0..w0+1, ch interleaved
    float4 c = *(const float4*)(px + 4);  // w0+2..w0+3
    vfloat4 ch0 = {a.x, a.z, c.x, c.z};
    vfloat4 ch1 = {a.y, a.w, c.y, c.w};
    __builtin_nontemporal_store(ch0, (vfloat4*)(out + obase));
    __builtin_nontemporal_store(ch1, (vfloat4*)(out + obase + HWTOT));
  }

  const int off2[9] = {0, 0, 524288, 655360, 688128, 696320, 698368, 698880, 699008};

#pragma unroll
  for (int lv = 1; lv <= 8; ++lv) {
    const int S = 512 >> lv;
    const float scale = 1.0f / (float)(1 << lv);
    // jax.image.resize bilinear = half-pixel centers + clamp-to-edge
    float sh = ((float)h + 0.5f) * scale - 0.5f;
    float fh0f = floorf(sh);
    float fh = sh - fh0f;
    int h0 = (int)fh0f;
    int h0c = h0 < 0 ? 0 : h0;
    int h1c = (h0 + 1 > S - 1) ? (S - 1) : (h0 + 1);
    const float2* R0 = pyr + off2[lv] + (size_t)(b * S + h0c) * S;
    const float2* R1 = pyr + off2[lv] + (size_t)(b * S + h1c) * S;
    const float wy0 = 1.0f - fh;

    float o0[4], o1[4];
#pragma unroll
    for (int k = 0; k < 4; ++k) {
      float sw = ((float)(w0pix + k) + 0.5f) * scale - 0.5f;
      float fw0f = floorf(sw);
      float fw = sw - fw0f;
      int w0 = (int)fw0f;
      int w0c = w0 < 0 ? 0 : w0;
      int w1c = (w0 + 1 > S - 1) ? (S - 1) : (w0 + 1);
      float2 v00 = R0[w0c], v01 = R0[w1c];
      float2 v10 = R1[w0c], v11 = R1[w1c];
      float wx0 = 1.0f - fw;
      float tx_ = v00.x * wx0 + v01.x * fw;
      float bx_ = v10.x * wx0 + v11.x * fw;
      float ty_ = v00.y * wx0 + v01.y * fw;
      float by_ = v10.y * wx0 + v11.y * fw;
      o0[k] = tx_ * wy0 + bx_ * fh;
      o1[k] = ty_ * wy0 + by_ * fh;
    }
    vfloat4 c0 = {o0[0], o0[1], o0[2], o0[3]};
    vfloat4 c1 = {o1[0], o1[1], o1[2], o1[3]};
    __builtin_nontemporal_store(c0, (vfloat4*)(out + obase + (size_t)(2 * lv) * HWTOT));
    __builtin_nontemporal_store(c1, (vfloat4*)(out + obase + (size_t)(2 * lv + 1) * HWTOT));
  }
}

extern "C" void kernel_launch(void* const* d_in, const int* in_sizes, int n_in,
                              void* d_out, int out_size, void* d_ws, size_t ws_size,
                              hipStream_t stream) {
  const float* x = (const float*)d_in[0];
  float* out = (float*)d_out;
  float2* pyr = (float2*)d_ws;

  build_levels_1_6<<<dim3(64, 8), 256, 0, stream>>>(x, pyr);
  build_levels_7_8<<<dim3(8), 64, 0, stream>>>(pyr);
  upsample_all<<<dim3(256, 8), 256, 0, stream>>>(x, pyr, out);
}